// Round 3
// baseline (257.128 us; speedup 1.0000x reference)
//
#include <hip/hip_runtime.h>

typedef unsigned long long u64;

#define HW    3136      // 56*56
#define CIN   256
#define CMID  768
#define EPSV  1e-5

// ---------------------------------------------------------------------------
// prep: pack weight sign bits (bit=1 <=> w<0); layer-1 BN folded to integer
// threshold t1[o] (sign(y1bn)<0 <=> 2p > t1, p = popc mismatches);
// layer-2 BN folded to float2 (A2,B2): y2 = p*A2 + B2.
// ---------------------------------------------------------------------------
__global__ __launch_bounds__(64) void prep_kernel(
    const float* __restrict__ w1, const float* __restrict__ w2,
    const float* __restrict__ g1, const float* __restrict__ b1,
    const float* __restrict__ m1, const float* __restrict__ v1,
    const float* __restrict__ g2, const float* __restrict__ b2,
    const float* __restrict__ m2, const float* __restrict__ v2,
    u64* __restrict__ pw1, u64* __restrict__ pw2,
    int* __restrict__ t1, float2* __restrict__ ab2)
{
  int blk  = blockIdx.x;
  int lane = threadIdx.x;
  if (blk < 3072) {                       // w1: 768 rows x 4 words
    int o = blk >> 2, seg = blk & 3;
    u64 msk = __ballot(w1[o * CIN + (seg << 6) + lane] < 0.0f);
    if (lane == 0) pw1[blk] = msk;
  } else if (blk < 6144) {                // w2: 256 rows x 12 words
    int i = blk - 3072;
    int o = i / 12, seg = i - o * 12;
    u64 msk = __ballot(w2[o * CMID + (seg << 6) + lane] < 0.0f);
    if (lane == 0) pw2[i] = msk;
  } else {                                // BN constants
    int i = ((blk - 6144) << 6) + lane;
    if (i < CMID) {
      double inv = (double)g1[i] / sqrt((double)v1[i] + EPSV);
      double c   = (double)b1[i] - (double)m1[i] * inv;
      // y1bn < 0  <=>  2p > 256 + c/inv   (inv > 0 always)
      t1[i] = (int)floor(256.0 + c / inv);
    } else if (i < CMID + CIN) {
      int j = i - CMID;
      double inv = (double)g2[j] / sqrt((double)v2[j] + EPSV);
      float2 o2;
      o2.x = (float)(-2.0 * inv);
      o2.y = (float)(768.0 * inv + (double)b2[j] - (double)m2[j] * inv);
      ab2[j] = o2;
    }
  }
}

// ---------------------------------------------------------------------------
// main: one thread = one whole pixel. Weight row index is wave-uniform ->
// weights + thresholds stream through SGPRs (s_load), xor is v^s, no LDS,
// no shuffles, no __syncthreads. 64-thread blocks for load balance.
// ---------------------------------------------------------------------------
__global__ __launch_bounds__(64) void bnn_kernel(
    const float* __restrict__ x,
    const u64* __restrict__ pw1, const u64* __restrict__ pw2,
    const int* __restrict__ t1, const float2* __restrict__ ab2,
    float* __restrict__ out)
{
  int px = blockIdx.x * 64 + threadIdx.x;   // 1568*64 == 100352 exactly
  int b  = px / HW;
  int hw = px - b * HW;
  const float* xp = x   + (size_t)b * (CIN * HW) + hw;
  float*       op = out + (size_t)b * (CIN * HW) + hw;

  // ---- pack sign(x): bit=1 <=> x<0; track min|x| for exact-zero detect ----
  u64 sx[4] = {0, 0, 0, 0};
  float mn = 1e30f;
  #pragma unroll 8
  for (int c = 0; c < CIN; ++c) {
    float v = xp[(size_t)c * HW];
    sx[c >> 6] |= (u64)(__float_as_uint(v) >> 31) << (c & 63);
    mn = fminf(mn, __builtin_fabsf(v));
  }

  // ---- layer 1: 768 rows, weights via SGPR stream ----
  u64 sy[12];
  #pragma unroll
  for (int j = 0; j < 12; ++j) sy[j] = 0ull;

  #pragma unroll 4
  for (int o = 0; o < CMID; ++o) {
    const u64* w = pw1 + (size_t)(o << 2);      // wave-uniform -> s_load
    int pa = __popcll(w[0] ^ sx[0]) + __popcll(w[1] ^ sx[1]);
    int pb = __popcll(w[2] ^ sx[2]) + __popcll(w[3] ^ sx[3]);
    int p  = pa + pb;
    sy[o >> 6] |= (u64)(unsigned)((p + p) > t1[o]) << (o & 63);
  }

  // ---- rare exact path: x has a 0.0 channel (jnp.sign(0)==0) ----
  if (mn == 0.0f) {
    u64 zx[4] = {0, 0, 0, 0};
    for (int c = 0; c < CIN; ++c)
      zx[c >> 6] |= (u64)(xp[(size_t)c * HW] == 0.0f ? 1u : 0u) << (c & 63);
    int K0 = __popcll(zx[0]) + __popcll(zx[1]) + __popcll(zx[2]) + __popcll(zx[3]);
    #pragma unroll
    for (int j = 0; j < 12; ++j) sy[j] = 0ull;
    for (int o = 0; o < CMID; ++o) {
      const u64* w = pw1 + (size_t)(o << 2);
      u64 d0 = w[0] ^ sx[0], d1 = w[1] ^ sx[1];
      u64 d2 = w[2] ^ sx[2], d3 = w[3] ^ sx[3];
      int p  = __popcll(d0) + __popcll(d1) + __popcll(d2) + __popcll(d3);
      int dz = __popcll(d0 & zx[0]) + __popcll(d1 & zx[1]) +
               __popcll(d2 & zx[2]) + __popcll(d3 & zx[3]);
      // y1_exact sign: (2p + K0 - 2dz) > t1
      sy[o >> 6] |= (u64)(unsigned)((p + p + K0 - dz - dz) > t1[o]) << (o & 63);
    }
  }

  // ---- layer 2: 256 rows, weights via SGPR stream, BN + residual ----
  #pragma unroll 2
  for (int o = 0; o < CIN; ++o) {
    const u64* w = pw2 + (size_t)o * 12;        // wave-uniform -> s_load
    int pa = __popcll(w[0] ^ sy[0]) + __popcll(w[1]  ^ sy[1])
           + __popcll(w[2] ^ sy[2]) + __popcll(w[3]  ^ sy[3])
           + __popcll(w[4] ^ sy[4]) + __popcll(w[5]  ^ sy[5]);
    int pb = __popcll(w[6] ^ sy[6]) + __popcll(w[7]  ^ sy[7])
           + __popcll(w[8] ^ sy[8]) + __popcll(w[9]  ^ sy[9])
           + __popcll(w[10] ^ sy[10]) + __popcll(w[11] ^ sy[11]);
    float2 ab = ab2[o];
    float y = fmaf((float)(pa + pb), ab.x, ab.y);
    op[(size_t)o * HW] = y + xp[(size_t)o * HW];
  }
}

extern "C" void kernel_launch(void* const* d_in, const int* in_sizes, int n_in,
                              void* d_out, int out_size, void* d_ws, size_t ws_size,
                              hipStream_t stream) {
  const float* x  = (const float*)d_in[0];
  const float* w1 = (const float*)d_in[1];
  const float* w2 = (const float*)d_in[2];
  const float* g1 = (const float*)d_in[3];
  const float* b1 = (const float*)d_in[4];
  const float* m1 = (const float*)d_in[5];
  const float* v1 = (const float*)d_in[6];
  const float* g2 = (const float*)d_in[7];
  const float* b2 = (const float*)d_in[8];
  const float* m2 = (const float*)d_in[9];
  const float* v2 = (const float*)d_in[10];
  float* out = (float*)d_out;

  u64*    pw1 = (u64*)d_ws;
  u64*    pw2 = pw1 + 3072;
  int*    t1  = (int*)(pw2 + 3072);
  float2* ab2 = (float2*)(t1 + CMID);

  prep_kernel<<<6160, 64, 0, stream>>>(w1, w2, g1, b1, m1, v1,
                                       g2, b2, m2, v2, pw1, pw2, t1, ab2);
  bnn_kernel<<<1568, 64, 0, stream>>>(x, pw1, pw2, t1, ab2, out);
}

// Round 4
// 156.393 us; speedup vs baseline: 1.6441x; 1.6441x over previous
//
#include <hip/hip_runtime.h>

typedef unsigned long long u64;

#define HW    3136      // 56*56
#define CIN   256
#define CMID  768
#define EPSV  1e-5

// ---------------------------------------------------------------------------
// prep: pack weight sign bits (bit=1 <=> w<0); layer-1 BN folded to integer
// threshold t1[o] (sign(y1bn)<0 <=> 2p > t1, p = popc mismatches);
// layer-2 BN folded to float2 (A2,B2): y2 = p*A2 + B2.
// ---------------------------------------------------------------------------
__global__ __launch_bounds__(64) void prep_kernel(
    const float* __restrict__ w1, const float* __restrict__ w2,
    const float* __restrict__ g1, const float* __restrict__ b1,
    const float* __restrict__ m1, const float* __restrict__ v1,
    const float* __restrict__ g2, const float* __restrict__ b2,
    const float* __restrict__ m2, const float* __restrict__ v2,
    u64* __restrict__ pw1, u64* __restrict__ pw2,
    int* __restrict__ t1, float2* __restrict__ ab2)
{
  int blk  = blockIdx.x;
  int lane = threadIdx.x;
  if (blk < 3072) {                       // w1: 768 rows x 4 words
    int o = blk >> 2, seg = blk & 3;
    u64 msk = __ballot(w1[o * CIN + (seg << 6) + lane] < 0.0f);
    if (lane == 0) pw1[blk] = msk;
  } else if (blk < 6144) {                // w2: 256 rows x 12 words
    int i = blk - 3072;
    int o = i / 12, seg = i - o * 12;
    u64 msk = __ballot(w2[o * CMID + (seg << 6) + lane] < 0.0f);
    if (lane == 0) pw2[i] = msk;
  } else {                                // BN constants
    int i = ((blk - 6144) << 6) + lane;
    if (i < CMID) {
      double inv = (double)g1[i] / sqrt((double)v1[i] + EPSV);
      double c   = (double)b1[i] - (double)m1[i] * inv;
      // y1bn < 0  <=>  2p > 256 + c/inv   (inv > 0 always)
      t1[i] = (int)floor(256.0 + c / inv);
    } else if (i < CMID + CIN) {
      int j = i - CMID;
      double inv = (double)g2[j] / sqrt((double)v2[j] + EPSV);
      float2 o2;
      o2.x = (float)(-2.0 * inv);
      o2.y = (float)(768.0 * inv + (double)b2[j] - (double)m2[j] * inv);
      ab2[j] = o2;
    }
  }
}

// ---------------------------------------------------------------------------
// main: block = 4 waves over the SAME 64 pixels; wave w owns layer-1 rows
// [192w,192w+192) and layer-2 rows [64w,64w+64). Row index is wave-uniform ->
// all weight/threshold LDS reads are broadcasts (conflict-free). Partial sign
// words exchanged via small ssy buffer. W1 and W2 phase-share one 24KB LDS
// region so 4 blocks fit per CU (16 waves/CU).
// ---------------------------------------------------------------------------
__global__ __launch_bounds__(256, 4) void bnn_kernel(
    const float* __restrict__ x,
    const u64* __restrict__ pw1, const u64* __restrict__ pw2,
    const int* __restrict__ t1g, const float2* __restrict__ ab2g,
    float* __restrict__ out)
{
  __shared__ __align__(16) u64 swt[3072];   // 24 KB: W1, then W2
  __shared__ int    st1[CMID];              // 3 KB
  __shared__ float2 sab2[CIN];              // 2 KB
  __shared__ u64    ssy[64][13];            // 6.5 KB (pad 13 vs bank stride)
                                            // total 36,352 B -> 4 blocks/CU
  int t    = threadIdx.x;
  int w    = t >> 6;
  int lane = t & 63;

  for (int i = t; i < 3072; i += 256) swt[i] = pw1[i];
  for (int i = t; i < CMID; i += 256) st1[i] = t1g[i];
  for (int i = t; i < CIN;  i += 256) sab2[i] = ab2g[i];
  __syncthreads();

  int px = blockIdx.x * 64 + lane;          // 1568*64 == 100352 exactly
  int b  = px / HW;
  int hw = px - b * HW;
  const float* xp = x   + (size_t)b * (CIN * HW) + hw;
  float*       op = out + (size_t)b * (CIN * HW) + hw;

  // ---- pack sign(x) (bit=1 <=> x<0); 4 min-accumulators detect exact zeros
  u64 sx[4] = {0, 0, 0, 0};
  unsigned mz0 = ~0u, mz1 = ~0u, mz2 = ~0u, mz3 = ~0u;
  #pragma unroll 8
  for (int c = 0; c < CIN; ++c) {
    unsigned u = __float_as_uint(xp[(size_t)c * HW]);
    sx[c >> 6] |= (u64)(u >> 31) << (c & 63);
    unsigned m = u + u;                     // clears sign bit; 0 <=> x==+-0.0
    if      ((c & 3) == 0) mz0 = mz0 < m ? mz0 : m;
    else if ((c & 3) == 1) mz1 = mz1 < m ? mz1 : m;
    else if ((c & 3) == 2) mz2 = mz2 < m ? mz2 : m;
    else                   mz3 = mz3 < m ? mz3 : m;
  }
  unsigned mza = mz0 < mz1 ? mz0 : mz1;
  unsigned mzb = mz2 < mz3 ? mz2 : mz3;
  bool hasZero = ((mza < mzb ? mza : mzb) == 0u);

  // ---- layer 1: this wave's 192 rows (wave-uniform -> broadcast reads) ----
  int base = w * 192;
  u64 a0 = 0, a1 = 0, a2 = 0;
  #pragma unroll
  for (int k = 0; k < 3; ++k) {
    u64 a = 0;
    int rb = base + (k << 6);
    #pragma unroll 4
    for (int i = 0; i < 64; ++i) {
      int o = rb + i;
      ulonglong2 wa = *(const ulonglong2*)&swt[(size_t)(o << 2)];
      ulonglong2 wb = *(const ulonglong2*)&swt[(size_t)(o << 2) + 2];
      int pa = __popcll(wa.x ^ sx[0]) + __popcll(wa.y ^ sx[1]);
      int pb = __popcll(wb.x ^ sx[2]) + __popcll(wb.y ^ sx[3]);
      int p  = pa + pb;
      a |= (u64)(unsigned)((p + p) > st1[o]) << i;
    }
    if (k == 0) a0 = a; else if (k == 1) a1 = a; else a2 = a;
  }

  // ---- rare exact path: pixel has a 0.0 channel (jnp.sign(0)==0) ----
  if (__builtin_expect(hasZero, 0)) {
    u64 zx[4] = {0, 0, 0, 0};
    for (int c = 0; c < CIN; ++c) {
      unsigned u = __float_as_uint(xp[(size_t)c * HW]);
      zx[c >> 6] |= (u64)((u + u) == 0u ? 1u : 0u) << (c & 63);
    }
    int K0 = __popcll(zx[0]) + __popcll(zx[1]) + __popcll(zx[2]) + __popcll(zx[3]);
    for (int k = 0; k < 3; ++k) {
      u64 a = 0;
      int rb = base + (k << 6);
      for (int i = 0; i < 64; ++i) {
        int o = rb + i;
        ulonglong2 wa = *(const ulonglong2*)&swt[(size_t)(o << 2)];
        ulonglong2 wb = *(const ulonglong2*)&swt[(size_t)(o << 2) + 2];
        u64 d0 = wa.x ^ sx[0], d1 = wa.y ^ sx[1];
        u64 d2 = wb.x ^ sx[2], d3 = wb.y ^ sx[3];
        int p  = __popcll(d0) + __popcll(d1) + __popcll(d2) + __popcll(d3);
        int dz = __popcll(d0 & zx[0]) + __popcll(d1 & zx[1]) +
                 __popcll(d2 & zx[2]) + __popcll(d3 & zx[3]);
        // exact: (2p + K0 - 2dz) > t1
        a |= (u64)(unsigned)((p + p + K0 - dz - dz) > st1[o]) << i;
      }
      if (k == 0) a0 = a; else if (k == 1) a1 = a; else a2 = a;
    }
  }

  ssy[lane][3 * w + 0] = a0;
  ssy[lane][3 * w + 1] = a1;
  ssy[lane][3 * w + 2] = a2;
  __syncthreads();

  // ---- swap in W2 over the same LDS region ----
  for (int i = t; i < 3072; i += 256) swt[i] = pw2[i];
  __syncthreads();

  // ---- layer 2: this wave's 64 rows, BN + residual ----
  u64 sy[12];
  #pragma unroll
  for (int j = 0; j < 12; ++j) sy[j] = ssy[lane][j];

  int ob = w << 6;
  #pragma unroll 2
  for (int j = 0; j < 64; ++j) {
    int o = ob + j;
    const u64* wr = &swt[(size_t)o * 12];
    ulonglong2 w0v = *(const ulonglong2*)(wr + 0);
    ulonglong2 w1v = *(const ulonglong2*)(wr + 2);
    ulonglong2 w2v = *(const ulonglong2*)(wr + 4);
    ulonglong2 w3v = *(const ulonglong2*)(wr + 6);
    ulonglong2 w4v = *(const ulonglong2*)(wr + 8);
    ulonglong2 w5v = *(const ulonglong2*)(wr + 10);
    int pa = __popcll(w0v.x ^ sy[0]) + __popcll(w0v.y ^ sy[1])
           + __popcll(w1v.x ^ sy[2]) + __popcll(w1v.y ^ sy[3])
           + __popcll(w2v.x ^ sy[4]) + __popcll(w2v.y ^ sy[5]);
    int pb = __popcll(w3v.x ^ sy[6]) + __popcll(w3v.y ^ sy[7])
           + __popcll(w4v.x ^ sy[8]) + __popcll(w4v.y ^ sy[9])
           + __popcll(w5v.x ^ sy[10]) + __popcll(w5v.y ^ sy[11]);
    float2 ab = sab2[o];
    float y = fmaf((float)(pa + pb), ab.x, ab.y);
    op[(size_t)o * HW] = y + xp[(size_t)o * HW];
  }
}

extern "C" void kernel_launch(void* const* d_in, const int* in_sizes, int n_in,
                              void* d_out, int out_size, void* d_ws, size_t ws_size,
                              hipStream_t stream) {
  const float* x  = (const float*)d_in[0];
  const float* w1 = (const float*)d_in[1];
  const float* w2 = (const float*)d_in[2];
  const float* g1 = (const float*)d_in[3];
  const float* b1 = (const float*)d_in[4];
  const float* m1 = (const float*)d_in[5];
  const float* v1 = (const float*)d_in[6];
  const float* g2 = (const float*)d_in[7];
  const float* b2 = (const float*)d_in[8];
  const float* m2 = (const float*)d_in[9];
  const float* v2 = (const float*)d_in[10];
  float* out = (float*)d_out;

  u64*    pw1 = (u64*)d_ws;
  u64*    pw2 = pw1 + 3072;
  int*    t1  = (int*)(pw2 + 3072);
  float2* ab2 = (float2*)(t1 + CMID);

  prep_kernel<<<6160, 64, 0, stream>>>(w1, w2, g1, b1, m1, v1,
                                       g2, b2, m2, v2, pw1, pw2, t1, ab2);
  bnn_kernel<<<1568, 256, 0, stream>>>(x, pw1, pw2, t1, ab2, out);
}